// Round 11
// baseline (251.499 us; speedup 1.0000x reference)
//
#include <hip/hip_runtime.h>

#define M_TOTAL 8192
#define KDIM 1024
#define TASKS 20
#define SBUF 256

typedef __attribute__((ext_vector_type(4))) int i32x4;
typedef __attribute__((ext_vector_type(8))) int i32x8;
typedef __attribute__((ext_vector_type(4))) float f32x4;

__device__ __forceinline__ void gload_lds16(const void* g, char* l) {
  __builtin_amdgcn_global_load_lds((const __attribute__((address_space(1))) void*)g,
                                   (__attribute__((address_space(3))) void*)l, 16, 0, 0);
}

#define FENCE() asm volatile("" ::: "memory")
#define BAR() do { FENCE(); __builtin_amdgcn_s_barrier(); FENCE(); } while (0)
#define LGKM0() asm volatile("s_waitcnt lgkmcnt(0)" ::: "memory")
#define VMC(n) asm volatile("s_waitcnt vmcnt(" #n ")" ::: "memory")
#define SCHED0() __builtin_amdgcn_sched_barrier(0)
// All scale bytes = 0x7F (E8M0 exponent 0 -> x1.0): plain fp8 GEMM at MX rate,
// immune to scale block/opsel mapping details. cbsz=0/blgp=0 = e4m3 A and B.
#define MFMA_(a, bb, c) \
  (c) = __builtin_amdgcn_mfma_scale_f32_16x16x128_f8f6f4((a), (bb), (c), 0, 0, \
                                                         0, 0x7F7F7F7F, 0, 0x7F7F7F7F)

// One block per row: L2-normalize a 1024-float row of X or W, emit fp8 e4m3
// (RNE via v_cvt_pk_fp8_f32 — unbiased). First 640 blocks also init out[]
// to -1e30 for the atomicMin combine (runs before gemm in stream order).
__global__ __launch_bounds__(256) void norm_rows_kernel(const float* __restrict__ X,
                                                        const float* __restrict__ W,
                                                        unsigned int* __restrict__ Xq,
                                                        unsigned int* __restrict__ Wq,
                                                        float* __restrict__ out) {
  const int row = blockIdx.x;
  const int tid = threadIdx.x;
  if (row < (M_TOTAL * TASKS) / 256) out[row * 256 + tid] = -1e30f;
  const float* in;
  unsigned int* outp;
  int r;
  if (row < M_TOTAL) { in = X; outp = Xq; r = row; }
  else               { in = W; outp = Wq; r = row - M_TOTAL; }
  const float4 v = ((const float4*)(in + (size_t)r * KDIM))[tid];
  float s = v.x * v.x + v.y * v.y + v.z * v.z + v.w * v.w;
#pragma unroll
  for (int off = 32; off >= 1; off >>= 1) s += __shfl_xor(s, off, 64);
  __shared__ float part[4];
  if ((tid & 63) == 0) part[tid >> 6] = s;
  __syncthreads();
  s = part[0] + part[1] + part[2] + part[3];
  const float sc = rsqrtf(s);
  int pk = __builtin_amdgcn_cvt_pk_fp8_f32(v.x * sc, v.y * sc, 0, false);
  pk = __builtin_amdgcn_cvt_pk_fp8_f32(v.z * sc, v.w * sc, pk, true);
  outp[(size_t)r * (KDIM / 4) + tid] = (unsigned int)pk;
}

// 128(M) x 128(N) x BK=128 fp8-MX tile. 256 thr = 4 waves (2M x 2N), wave tile
// 64x64: acc[4][4]. 2 blocks/CU (LDS 66.5 KB). 2560 blocks = 5 dispatch rounds.
// LDS per buf (32 KB at B_*32768): A [0,16K) rows of 128 B, B [16K,32K).
// Swizzle: 16B granule slot' = c16 ^ (row&7) within each row's 128B line.
// Stage dest is linear (granule G = ii*256+tid -> byte G*16); SOURCE
// c16 = (tid&7) ^ ((tid>>3)&7) is the inverse permutation (rule #21).
// 8 K-tiles, r6-proven 2-barrier KTILE, counted VMC(8) 2-deep ledger.
// *** r10 bugfix: fragments are built with __builtin_shufflevector from two
// well-defined i32x4 loads — r10's typed-store punning into i32x8 was
// strict-aliasing UB; TBAA killed the bF stores, bF folded to undef, backend
// reused aF's registers -> C = A*A^T (diag dots ~1 -> out ~ -1/32, the exact
// 1.375-0.03125 = 1.34375 error signature). No typed stores anywhere now. ***
__global__ __launch_bounds__(256, 2) void gemm_min_kernel(const unsigned char* __restrict__ Xq,
                                                          const unsigned char* __restrict__ Wq,
                                                          float* __restrict__ out) {
  __shared__ __align__(16) char sm[66560];

  const int tid = threadIdx.x;
  const int lane = tid & 63;
  const int w = tid >> 6, wr = w >> 1, wc = w & 1;
  const int lrow = lane & 15, lgrp = lane >> 4;

  // XCD swizzle: 2560 blocks; xcd owns an 8-mblk stripe, mblk fastest, nblk slow.
  const int o = blockIdx.x;
  const int xcd = o & 7, i = o >> 3;        // i in [0,320)
  const int nblk = i >> 3;                   // 0..39
  const int mblk = xcd * 8 + (i & 7);        // 0..63
  const int rowBase = mblk * 128;
  const int col0 = nblk * 128;
  const int task = nblk >> 1;

  // staging source decode (inverse of slot' = c16 ^ (row&7)); chunk ii adds
  // 32 rows (ii*32*KDIM source, ii*4096 linear dest) — c16 is chunk-invariant.
  const int c16 = (tid & 7) ^ ((tid >> 3) & 7);
  const unsigned char* pA = Xq + (size_t)(rowBase + (tid >> 3)) * KDIM + c16 * 16;
  const unsigned char* pB = Wq + (size_t)(col0 + (tid >> 3)) * KDIM + c16 * 16;

  // frag read bases: row = (wr|wc)*64 + m*16 + lrow (row&7 = lrow&7);
  // logical granules lgrp*2, lgrp*2+1 -> phys = (lgrp*2)^(lrow&7), that ^1
  // (offset XOR 16 flips granule bit0; XOR applied to the offset, not the ptr).
  const int slot = ((lgrp * 2) ^ (lrow & 7)) * 16;
  const int aBase = (wr * 64 + lrow) * 128 + slot;
  const int bBase = 16384 + (wc * 64 + lrow) * 128 + slot;

  f32x4 acc[4][4] = {};

  // 8 loads/thread/K-tile into buf B_: A chunks 0..3 (128 rows), B chunks 0..3
#define STG(B_, kB) do { \
    _Pragma("unroll") for (int ii = 0; ii < 4; ++ii) { \
      gload_lds16(pA + (size_t)ii * 32 * KDIM + (kB), sm + (B_) * 32768 + ii * 4096 + tid * 16); \
      gload_lds16(pB + (size_t)ii * 32 * KDIM + (kB), sm + (B_) * 32768 + 16384 + ii * 4096 + tid * 16); \
    } } while (0)

  // well-defined 32-byte fragment load: two i32x4 LDS reads + shufflevector
#define LD32(dst, base_, off_) do { \
    i32x4 lo_ = *(const i32x4*)((base_) + (off_)); \
    i32x4 hi_ = *(const i32x4*)((base_) + ((off_) ^ 16)); \
    (dst) = __builtin_shufflevector(lo_, hi_, 0, 1, 2, 3, 4, 5, 6, 7); \
  } while (0)

  // prologue: tile0 -> buf0, tile1 -> buf1; VMC(8) -> tile0 resident
  STG(0, 0);
  STG(1, 128);
  VMC(8); SCHED0();
  BAR();

  // Per K-tile: Ph1 {16 ds_read, MFMA n0..1, lgkm-drain, BAR};
  //             Ph2 {stage t+2 -> own buf, VMC(8) [t+1 resident], MFMA n2..3, BAR}.
#define KTILE(B_, kt) do { \
    i32x8 aF[4], bF[4]; \
    const char* base = sm + (B_) * 32768; \
    _Pragma("unroll") for (int m = 0; m < 4; ++m) LD32(aF[m], base, aBase + m * 2048); \
    _Pragma("unroll") for (int n = 0; n < 4; ++n) LD32(bF[n], base, bBase + n * 2048); \
    __builtin_amdgcn_s_setprio(1); \
    _Pragma("unroll") for (int m = 0; m < 4; ++m) { MFMA_(aF[m], bF[0], acc[m][0]); MFMA_(aF[m], bF[1], acc[m][1]); } \
    __builtin_amdgcn_s_setprio(0); \
    LGKM0(); SCHED0(); \
    BAR(); \
    { const int kB = ((kt) + 2 < 8) ? ((kt) + 2) * 128 : 0; STG(B_, kB); } \
    VMC(8); SCHED0(); \
    __builtin_amdgcn_s_setprio(1); \
    _Pragma("unroll") for (int m = 0; m < 4; ++m) { MFMA_(aF[m], bF[2], acc[m][2]); MFMA_(aF[m], bF[3], acc[m][3]); } \
    __builtin_amdgcn_s_setprio(0); \
    BAR(); \
  } while (0)

  for (int kt = 0; kt < 8; kt += 2) {
    KTILE(0, kt);
    KTILE(1, kt + 1);
  }

  // Drain wrap-garbage stages before reusing LDS / ending the block (r5 race).
  VMC(0); SCHED0();
  BAR();

  // epilogue: per-row max-dot over 4 n-frags + 16 col-lanes -> red -> atomic.
  // C/D layout (shape-determined): col=lane&15, row=lgrp*4+reg.
  float (*red)[2] = (float (*)[2])(sm + 65536);  // outside staging regions
#pragma unroll
  for (int m = 0; m < 4; ++m) {
#pragma unroll
    for (int rr = 0; rr < 4; ++rr) {
      float v = fmaxf(fmaxf(acc[m][0][rr], acc[m][1][rr]), fmaxf(acc[m][2][rr], acc[m][3][rr]));
      v = fmaxf(v, __shfl_xor(v, 1, 64));
      v = fmaxf(v, __shfl_xor(v, 2, 64));
      v = fmaxf(v, __shfl_xor(v, 4, 64));
      v = fmaxf(v, __shfl_xor(v, 8, 64));
      if (lrow == 0) red[wr * 64 + m * 16 + lgrp * 4 + rr][wc] = v;
    }
  }
  BAR();
  if (tid < 128) {
    const float vv = fmaxf(red[tid][0], red[tid][1]);
    const float d = sqrtf(fmaxf(2.0f - 2.0f * vv, 1e-12f));
    // all published values negative: uint atomicMin == float max == -min dist
    atomicMin((unsigned int*)&out[(size_t)(rowBase + tid) * TASKS + task],
              __float_as_uint(-d));
  }
#undef KTILE
#undef LD32
#undef STG
}

extern "C" void kernel_launch(void* const* d_in, const int* in_sizes, int n_in,
                              void* d_out, int out_size, void* d_ws, size_t ws_size,
                              hipStream_t stream) {
  const float* X = (const float*)d_in[0];   // (8192, 1024) fp32
  const float* W = (const float*)d_in[1];   // (5120, 1024) fp32
  float* out = (float*)d_out;               // (8192, 20) fp32

  unsigned char* Xq = (unsigned char*)d_ws;                          // 8.4 MB fp8
  unsigned char* Wq = Xq + (size_t)M_TOTAL * KDIM;                   // 5.2 MB fp8

  norm_rows_kernel<<<M_TOTAL + TASKS * SBUF, 256, 0, stream>>>(
      X, W, (unsigned int*)Xq, (unsigned int*)Wq, out);
  gemm_min_kernel<<<2560, 256, 0, stream>>>(Xq, Wq, out);
}

// Round 12
// 102.115 us; speedup vs baseline: 2.4629x; 2.4629x over previous
//
#include <hip/hip_runtime.h>

#define M_TOTAL 8192
#define KDIM 1024
#define TASKS 20
#define SBUF 256

typedef __attribute__((ext_vector_type(4))) int i32x4;
typedef __attribute__((ext_vector_type(8))) int i32x8;
typedef __attribute__((ext_vector_type(4))) float f32x4;

__device__ __forceinline__ void gload_lds16(const void* g, char* l) {
  __builtin_amdgcn_global_load_lds((const __attribute__((address_space(1))) void*)g,
                                   (__attribute__((address_space(3))) void*)l, 16, 0, 0);
}

#define FENCE() asm volatile("" ::: "memory")
#define BAR() do { FENCE(); __builtin_amdgcn_s_barrier(); FENCE(); } while (0)
#define LGKM0() asm volatile("s_waitcnt lgkmcnt(0)" ::: "memory")
#define VMC(n) asm volatile("s_waitcnt vmcnt(" #n ")" ::: "memory")
#define SCHED0() __builtin_amdgcn_sched_barrier(0)
// All scale bytes = 0x7F (E8M0 exponent 0 -> x1.0): plain fp8 GEMM at MX rate,
// immune to scale block/opsel mapping details. cbsz=0/blgp=0 = e4m3 A and B.
#define MFMA_(a, bb, c) \
  (c) = __builtin_amdgcn_mfma_scale_f32_16x16x128_f8f6f4((a), (bb), (c), 0, 0, \
                                                         0, 0x7F7F7F7F, 0, 0x7F7F7F7F)

// One block per row: L2-normalize a 1024-float row of X or W, emit fp8 e4m3
// (RNE via v_cvt_pk_fp8_f32 — unbiased). First 640 blocks also init out[]
// to -1e30 for the atomicMin combine (runs before gemm in stream order).
__global__ __launch_bounds__(256) void norm_rows_kernel(const float* __restrict__ X,
                                                        const float* __restrict__ W,
                                                        unsigned int* __restrict__ Xq,
                                                        unsigned int* __restrict__ Wq,
                                                        float* __restrict__ out) {
  const int row = blockIdx.x;
  const int tid = threadIdx.x;
  if (row < (M_TOTAL * TASKS) / 256) out[row * 256 + tid] = -1e30f;
  const float* in;
  unsigned int* outp;
  int r;
  if (row < M_TOTAL) { in = X; outp = Xq; r = row; }
  else               { in = W; outp = Wq; r = row - M_TOTAL; }
  const float4 v = ((const float4*)(in + (size_t)r * KDIM))[tid];
  float s = v.x * v.x + v.y * v.y + v.z * v.z + v.w * v.w;
#pragma unroll
  for (int off = 32; off >= 1; off >>= 1) s += __shfl_xor(s, off, 64);
  __shared__ float part[4];
  if ((tid & 63) == 0) part[tid >> 6] = s;
  __syncthreads();
  s = part[0] + part[1] + part[2] + part[3];
  const float sc = rsqrtf(s);
  int pk = __builtin_amdgcn_cvt_pk_fp8_f32(v.x * sc, v.y * sc, 0, false);
  pk = __builtin_amdgcn_cvt_pk_fp8_f32(v.z * sc, v.w * sc, pk, true);
  outp[(size_t)r * (KDIM / 4) + tid] = (unsigned int)pk;
}

// 128(M) x 128(N) x BK=128 fp8-MX tile. 256 thr = 4 waves (2M x 2N), wave tile
// 64x64: acc[4][4]. 2 blocks/CU (LDS 66.5 KB caps residency). 2560 blocks.
// *** r11 fix: __launch_bounds__(256, 1). Under (256,2) the allocator pinned
// arch VGPR = accum_offset = 128 while the scale-MFMA form needs ~180 arch
// (64 frag regs + C/D in arch + addressing) -> ~50 regs spilled -> 623 MB of
// scratch writes/dispatch (r11 WRITE_SIZE), MfmaUtil 6.5%. Budget 512 removes
// the spill; LDS still caps at 2 blocks/CU so residency is unchanged. ***
// LDS per buf (32 KB at B_*32768): A [0,16K) rows of 128 B, B [16K,32K).
// Swizzle: 16B granule slot' = c16 ^ (row&7) within each row's 128B line.
// Stage dest is linear (granule G = ii*256+tid -> byte G*16); SOURCE
// c16 = (tid&7) ^ ((tid>>3)&7) is the inverse permutation (rule #21).
// 8 K-tiles, 2-barrier KTILE, counted VMC(8) 2-deep ledger. Fragments built
// with shufflevector from two i32x4 loads (r10 TBAA lesson: no typed stores).
__global__ __launch_bounds__(256, 1) void gemm_min_kernel(const unsigned char* __restrict__ Xq,
                                                          const unsigned char* __restrict__ Wq,
                                                          float* __restrict__ out) {
  __shared__ __align__(16) char sm[66560];

  const int tid = threadIdx.x;
  const int lane = tid & 63;
  const int w = tid >> 6, wr = w >> 1, wc = w & 1;
  const int lrow = lane & 15, lgrp = lane >> 4;

  // XCD swizzle: 2560 blocks; xcd owns an 8-mblk stripe, mblk fastest, nblk slow.
  // A stripe (1 MB) stays L2-resident per XCD for the whole run; each round's
  // 8 B-halves (1 MB) are fetched once per XCD.
  const int o = blockIdx.x;
  const int xcd = o & 7, i = o >> 3;        // i in [0,320)
  const int nblk = i >> 3;                   // 0..39
  const int mblk = xcd * 8 + (i & 7);        // 0..63
  const int rowBase = mblk * 128;
  const int col0 = nblk * 128;
  const int task = nblk >> 1;

  // staging source decode (inverse of slot' = c16 ^ (row&7)); chunk ii adds
  // 32 rows (ii*32*KDIM source, ii*4096 linear dest) — c16 is chunk-invariant.
  const int c16 = (tid & 7) ^ ((tid >> 3) & 7);
  const unsigned char* pA = Xq + (size_t)(rowBase + (tid >> 3)) * KDIM + c16 * 16;
  const unsigned char* pB = Wq + (size_t)(col0 + (tid >> 3)) * KDIM + c16 * 16;

  // frag read bases: row = (wr|wc)*64 + m*16 + lrow (row&7 = lrow&7);
  // logical granules lgrp*2, lgrp*2+1 -> phys = (lgrp*2)^(lrow&7), that ^1
  // (offset XOR 16 flips granule bit0).
  const int slot = ((lgrp * 2) ^ (lrow & 7)) * 16;
  const int aBase = (wr * 64 + lrow) * 128 + slot;
  const int bBase = 16384 + (wc * 64 + lrow) * 128 + slot;

  f32x4 acc[4][4] = {};

  // 8 loads/thread/K-tile into buf B_: A chunks 0..3 (128 rows), B chunks 0..3
#define STG(B_, kB) do { \
    _Pragma("unroll") for (int ii = 0; ii < 4; ++ii) { \
      gload_lds16(pA + (size_t)ii * 32 * KDIM + (kB), sm + (B_) * 32768 + ii * 4096 + tid * 16); \
      gload_lds16(pB + (size_t)ii * 32 * KDIM + (kB), sm + (B_) * 32768 + 16384 + ii * 4096 + tid * 16); \
    } } while (0)

  // well-defined 32-byte fragment load: two i32x4 LDS reads + shufflevector
#define LD32(dst, base_, off_) do { \
    i32x4 lo_ = *(const i32x4*)((base_) + (off_)); \
    i32x4 hi_ = *(const i32x4*)((base_) + ((off_) ^ 16)); \
    (dst) = __builtin_shufflevector(lo_, hi_, 0, 1, 2, 3, 4, 5, 6, 7); \
  } while (0)

  // prologue: tile0 -> buf0, tile1 -> buf1; VMC(8) -> tile0 resident
  STG(0, 0);
  STG(1, 128);
  VMC(8); SCHED0();
  BAR();

  // Per K-tile: Ph1 {16 ds_read, MFMA n0..1, lgkm-drain, BAR};
  //             Ph2 {stage t+2 -> own buf, VMC(8) [t+1 resident], MFMA n2..3, BAR}.
#define KTILE(B_, kt) do { \
    i32x8 aF[4], bF[4]; \
    const char* base = sm + (B_) * 32768; \
    _Pragma("unroll") for (int m = 0; m < 4; ++m) LD32(aF[m], base, aBase + m * 2048); \
    _Pragma("unroll") for (int n = 0; n < 4; ++n) LD32(bF[n], base, bBase + n * 2048); \
    __builtin_amdgcn_s_setprio(1); \
    _Pragma("unroll") for (int m = 0; m < 4; ++m) { MFMA_(aF[m], bF[0], acc[m][0]); MFMA_(aF[m], bF[1], acc[m][1]); } \
    __builtin_amdgcn_s_setprio(0); \
    LGKM0(); SCHED0(); \
    BAR(); \
    { const int kB = ((kt) + 2 < 8) ? ((kt) + 2) * 128 : 0; STG(B_, kB); } \
    VMC(8); SCHED0(); \
    __builtin_amdgcn_s_setprio(1); \
    _Pragma("unroll") for (int m = 0; m < 4; ++m) { MFMA_(aF[m], bF[2], acc[m][2]); MFMA_(aF[m], bF[3], acc[m][3]); } \
    __builtin_amdgcn_s_setprio(0); \
    BAR(); \
  } while (0)

  for (int kt = 0; kt < 8; kt += 2) {
    KTILE(0, kt);
    KTILE(1, kt + 1);
  }

  // Drain wrap-garbage stages before reusing LDS / ending the block (r5 race).
  VMC(0); SCHED0();
  BAR();

  // epilogue: per-row max-dot over 4 n-frags + 16 col-lanes -> red -> atomic.
  // C/D layout (shape-determined): col=lane&15, row=lgrp*4+reg.
  float (*red)[2] = (float (*)[2])(sm + 65536);  // outside staging regions
#pragma unroll
  for (int m = 0; m < 4; ++m) {
#pragma unroll
    for (int rr = 0; rr < 4; ++rr) {
      float v = fmaxf(fmaxf(acc[m][0][rr], acc[m][1][rr]), fmaxf(acc[m][2][rr], acc[m][3][rr]));
      v = fmaxf(v, __shfl_xor(v, 1, 64));
      v = fmaxf(v, __shfl_xor(v, 2, 64));
      v = fmaxf(v, __shfl_xor(v, 4, 64));
      v = fmaxf(v, __shfl_xor(v, 8, 64));
      if (lrow == 0) red[wr * 64 + m * 16 + lgrp * 4 + rr][wc] = v;
    }
  }
  BAR();
  if (tid < 128) {
    const float vv = fmaxf(red[tid][0], red[tid][1]);
    const float d = sqrtf(fmaxf(2.0f - 2.0f * vv, 1e-12f));
    // all published values negative: uint atomicMin == float max == -min dist
    atomicMin((unsigned int*)&out[(size_t)(rowBase + tid) * TASKS + task],
              __float_as_uint(-d));
  }
#undef KTILE
#undef LD32
#undef STG
}

extern "C" void kernel_launch(void* const* d_in, const int* in_sizes, int n_in,
                              void* d_out, int out_size, void* d_ws, size_t ws_size,
                              hipStream_t stream) {
  const float* X = (const float*)d_in[0];   // (8192, 1024) fp32
  const float* W = (const float*)d_in[1];   // (5120, 1024) fp32
  float* out = (float*)d_out;               // (8192, 20) fp32

  unsigned char* Xq = (unsigned char*)d_ws;                          // 8.4 MB fp8
  unsigned char* Wq = Xq + (size_t)M_TOTAL * KDIM;                   // 5.2 MB fp8

  norm_rows_kernel<<<M_TOTAL + TASKS * SBUF, 256, 0, stream>>>(
      X, W, (unsigned int*)Xq, (unsigned int*)Wq, out);
  gemm_min_kernel<<<2560, 256, 0, stream>>>(Xq, Wq, out);
}